// Round 2
// baseline (103.147 us; speedup 1.0000x reference)
//
#include <hip/hip_runtime.h>

// Problem constants (setup_inputs: [16,3,512,512] f32, patch 16)
#define N_   16
#define C_   3
#define H_   512
#define W_   512
#define P_   16
#define HP_  (H_ / P_)    // 32
#define WP_  (W_ / P_)    // 32
#define NC_  (N_ * C_)    // 48
#define NBLK_ (NC_ * HP_) // 1536

// Fused: per-strip patch-max -> per-block slot -> last block reduces to scalar.
// One block per (n, c, hp) strip: 16 rows x 512 cols, fully coalesced float4.
__global__ __launch_bounds__(256) void pl_fused(const float* __restrict__ outp,
                                                const float* __restrict__ tgtp,
                                                float* __restrict__ wsf,
                                                unsigned int* __restrict__ counter,
                                                float* __restrict__ res) {
    const int b  = blockIdx.x;       // (n*C + c)*HP + hp
    const int hp = b % HP_;
    const int nc = b / HP_;
    const int t  = threadIdx.x;

    const long long base4 = ((long long)nc * H_ + (long long)hp * P_) * (W_ / 4);
    const float4* __restrict__ o4 = (const float4*)outp + base4;
    const float4* __restrict__ t4 = (const float4*)tgtp + base4;

    float s = 0.0f;
#pragma unroll
    for (int r2 = 0; r2 < 8; ++r2) {
        float4 a = o4[r2 * 256 + t];
        float4 c = t4[r2 * 256 + t];
        s += fabsf(a.x - c.x) + fabsf(a.y - c.y) +
             fabsf(a.z - c.z) + fabsf(a.w - c.w);
    }

    // lanes {4g..4g+3} share one wp (thread t reads fixed col4 = t%128, wp = (t%128)/4)
    s += __shfl_xor(s, 1);
    s += __shfl_xor(s, 2);

    __shared__ float gsum[64];
    __shared__ int   lastFlag;
    if ((t & 3) == 0) gsum[t >> 2] = s;
    __syncthreads();

    if (t < 32) {
        float v = (gsum[t] + gsum[t + 32]) * (1.0f / (P_ * P_)); // patch mean
        for (int off = 16; off >= 1; off >>= 1)
            v = fmaxf(v, __shfl_xor(v, off));                    // max over 32 wp
        if (t == 0) {
            // publish strip max (device scope: per-XCD L2s not coherent)
            __hip_atomic_store(&wsf[b], v, __ATOMIC_RELEASE, __HIP_MEMORY_SCOPE_AGENT);
            unsigned old = __hip_atomic_fetch_add(counter, 1u, __ATOMIC_ACQ_REL,
                                                  __HIP_MEMORY_SCOPE_AGENT);
            // robust to any initial counter value (poison / replay accumulation):
            // each call adds exactly NBLK_, so exactly one block sees this residue.
            lastFlag = (((old + 1u) % (unsigned)NBLK_) == 0u) ? 1 : 0;
        }
    }
    __syncthreads();

    if (lastFlag) {
        float m = 0.0f;   // matches reference's max(., 0) seed; losses >= 0
        if (t < NC_) {
            for (int hp2 = 0; hp2 < HP_; ++hp2)
                m = fmaxf(m, __hip_atomic_load(&wsf[t * HP_ + hp2],
                                               __ATOMIC_RELAXED,
                                               __HIP_MEMORY_SCOPE_AGENT));
        }
        if (t < 64) {
            for (int off = 32; off >= 1; off >>= 1)
                m += __shfl_xor(m, off);
            if (t == 0) res[0] = m * (1.0f / NC_);
        }
    }
}

extern "C" void kernel_launch(void* const* d_in, const int* in_sizes, int n_in,
                              void* d_out, int out_size, void* d_ws, size_t ws_size,
                              hipStream_t stream) {
    const float* outp = (const float*)d_in[0];
    const float* tgtp = (const float*)d_in[1];
    float* res = (float*)d_out;
    float* wsf = (float*)d_ws;                          // NBLK_ slots
    unsigned int* counter = (unsigned int*)(wsf + NBLK_); // 1 slot, self-correcting mod NBLK_

    pl_fused<<<NBLK_, 256, 0, stream>>>(outp, tgtp, wsf, counter, res);
}

// Round 3
// 21.710 us; speedup vs baseline: 4.7510x; 4.7510x over previous
//
#include <hip/hip_runtime.h>

// Problem constants (setup_inputs: [16,3,512,512] f32, patch 16)
#define N_   16
#define C_   3
#define H_   512
#define W_   512
#define P_   16
#define HP_  (H_ / P_)    // 32
#define WP_  (W_ / P_)    // 32
#define NC_  (N_ * C_)    // 48
#define NBLK_ (NC_ * HP_) // 1536

// One block per (n, c, hp) strip: 16 rows x 512 cols. Plain store of the
// strip's patch-max into ws[hp*NC_+nc] (transposed for finalize). No atomics,
// no init: every slot is written every call.
__global__ __launch_bounds__(256) void pl_strips(const float* __restrict__ outp,
                                                 const float* __restrict__ tgtp,
                                                 float* __restrict__ ws) {
    const int b  = blockIdx.x;       // (n*C + c)*HP + hp
    const int hp = b % HP_;
    const int nc = b / HP_;
    const int t  = threadIdx.x;

    const long long base4 = ((long long)nc * H_ + (long long)hp * P_) * (W_ / 4);
    const float4* __restrict__ o4 = (const float4*)outp + base4;
    const float4* __restrict__ t4 = (const float4*)tgtp + base4;

    // Issue all 16 loads first: ~16 outstanding vmem ops/thread for latency hiding.
    float4 a[8], c[8];
#pragma unroll
    for (int r2 = 0; r2 < 8; ++r2) a[r2] = o4[r2 * 256 + t];
#pragma unroll
    for (int r2 = 0; r2 < 8; ++r2) c[r2] = t4[r2 * 256 + t];

    float s = 0.0f;
#pragma unroll
    for (int r2 = 0; r2 < 8; ++r2) {
        s += fabsf(a[r2].x - c[r2].x) + fabsf(a[r2].y - c[r2].y) +
             fabsf(a[r2].z - c[r2].z) + fabsf(a[r2].w - c[r2].w);
    }

    // Thread t always reads col4 = t%128 -> fixed wp = (t%128)/4.
    // lanes {4g..4g+3} share one wp.
    s += __shfl_xor(s, 1);
    s += __shfl_xor(s, 2);

    __shared__ float gsum[64];
    if ((t & 3) == 0) gsum[t >> 2] = s;
    __syncthreads();

    if (t < 32) {
        float v = (gsum[t] + gsum[t + 32]) * (1.0f / (P_ * P_)); // patch mean
        for (int off = 16; off >= 1; off >>= 1)
            v = fmaxf(v, __shfl_xor(v, off));                    // max over 32 wp
        if (t == 0) ws[hp * NC_ + nc] = v;                       // plain store
    }
}

// One block: reduce 1536 strip-maxes -> 48 per-(n,c) maxes -> mean -> scalar.
__global__ __launch_bounds__(256) void pl_finalize(const float* __restrict__ ws,
                                                   float* __restrict__ res) {
    __shared__ float sm[NBLK_];
    const int t = threadIdx.x;  // 256
#pragma unroll
    for (int i = 0; i < NBLK_ / 256; ++i) sm[t + i * 256] = ws[t + i * 256];
    __syncthreads();

    float v = 0.0f;  // matches reference's max(., 0) seed; losses >= 0
    if (t < NC_) {
        // transposed layout: sm[hp*NC_ + t] -> bank varies with t, conflict-free
        for (int hp = 0; hp < HP_; ++hp)
            v = fmaxf(v, sm[hp * NC_ + t]);
    }
    if (t < 64) {  // threads 0..47 live in wave 0; lanes 48..63 contribute 0
#pragma unroll
        for (int off = 32; off >= 1; off >>= 1)
            v += __shfl_xor(v, off);
        if (t == 0) res[0] = v * (1.0f / NC_);
    }
}

extern "C" void kernel_launch(void* const* d_in, const int* in_sizes, int n_in,
                              void* d_out, int out_size, void* d_ws, size_t ws_size,
                              hipStream_t stream) {
    const float* outp = (const float*)d_in[0];
    const float* tgtp = (const float*)d_in[1];
    float* res = (float*)d_out;
    float* ws  = (float*)d_ws;   // NBLK_ floats

    pl_strips<<<NBLK_, 256, 0, stream>>>(outp, tgtp, ws);
    pl_finalize<<<1, 256, 0, stream>>>(ws, res);
}